// Round 1
// baseline (245.816 us; speedup 1.0000x reference)
//
#include <hip/hip_runtime.h>

// SoftTree: out = (tree-path-probs from sigmoid(x@W+b)) @ leaves_weights
// x: [8192][512] f32, W: [512][1023] f32, b: [1023] f32, leaves: [1024][64] f32
// out: [8192][64] f32.  ws: p = sigmoid(x@W+b) stored as [8192][1024] (ld=1024).

#define M_DIM 8192
#define K_DIM 512
#define N_DIM 1023
#define LDP   1024

// ---------------- Kernel A: p = sigmoid(x @ W + b) ----------------
// Tile 128x64, BK=16, 256 threads, per-thread 8x4 micro-tile. fp32 VALU GEMM.
__global__ __launch_bounds__(256, 4) void gemm_sig(const float* __restrict__ x,
                                                   const float* __restrict__ W,
                                                   const float* __restrict__ bias,
                                                   float* __restrict__ p)
{
    const int BM = 128, BN = 64, BK = 16;
    __shared__ __align__(16) float As[16][128 + 4];   // +4 pad: write banks spread, rows stay 16B-aligned
    __shared__ __align__(16) float Bs[16][64 + 4];

    const int tid = threadIdx.x;
    const int m_base = blockIdx.y * BM;
    const int n_base = blockIdx.x * BN;

    const int tr = tid >> 4;          // 0..15 -> 8 rows each
    const int tc = tid & 15;          // 0..15 -> 4 cols each
    const int m0 = tr * 8;
    const int n0 = tc * 4;

    float acc[8][4];
    #pragma unroll
    for (int i = 0; i < 8; ++i)
        #pragma unroll
        for (int j = 0; j < 4; ++j) acc[i][j] = 0.f;

    const int arow = tid >> 2;         // 0..63
    const int acol = (tid & 3) * 4;    // 0,4,8,12
    const int bk   = tid >> 4;         // 0..15
    const int bn   = (tid & 15) * 4;   // 0..60

    for (int k0 = 0; k0 < K_DIM; k0 += BK) {
        // stage A tile (transposed to As[k][m]) — float4 global loads, 16B aligned
        #pragma unroll
        for (int i = 0; i < 2; ++i) {
            const int row = arow + i * 64;
            const float4 a = *reinterpret_cast<const float4*>(
                &x[(size_t)(m_base + row) * K_DIM + k0 + acol]);
            As[0][0 + (acol + 0) * (128 + 4) + row] = a.x;
            As[0][0 + (acol + 1) * (128 + 4) + row] = a.y;
            As[0][0 + (acol + 2) * (128 + 4) + row] = a.z;
            As[0][0 + (acol + 3) * (128 + 4) + row] = a.w;
        }
        // stage B tile (ldW=1023 is odd -> scalar loads), guard n<1023
        {
            const int gk = k0 + bk;
            #pragma unroll
            for (int j = 0; j < 4; ++j) {
                const int gn = n_base + bn + j;
                Bs[bk][bn + j] = (gn < N_DIM) ? W[(size_t)gk * N_DIM + gn] : 0.f;
            }
        }
        __syncthreads();

        #pragma unroll
        for (int kk = 0; kk < BK; ++kk) {
            const float4 b4 = *reinterpret_cast<const float4*>(&Bs[kk][n0]);
            const float4 a0 = *reinterpret_cast<const float4*>(&As[kk][m0]);
            const float4 a1 = *reinterpret_cast<const float4*>(&As[kk][m0 + 4]);
            const float a[8] = {a0.x, a0.y, a0.z, a0.w, a1.x, a1.y, a1.z, a1.w};
            const float b[4] = {b4.x, b4.y, b4.z, b4.w};
            #pragma unroll
            for (int i = 0; i < 8; ++i)
                #pragma unroll
                for (int j = 0; j < 4; ++j)
                    acc[i][j] = fmaf(a[i], b[j], acc[i][j]);
        }
        __syncthreads();
    }

    // epilogue: bias + sigmoid, store p (ld=1024)
    #pragma unroll
    for (int i = 0; i < 8; ++i) {
        const int gm = m_base + m0 + i;
        #pragma unroll
        for (int j = 0; j < 4; ++j) {
            const int gn = n_base + n0 + j;
            if (gn < N_DIM) {
                float v = acc[i][j] + bias[gn];
                v = 1.0f / (1.0f + __expf(-v));
                p[(size_t)gm * LDP + gn] = v;
            }
        }
    }
}

// ---------------- Kernel B: leaf probs + out = prob @ leaves ----------------
// 8 rows per block (leaves matrix re-read once per 8 rows), 256 threads.
__global__ __launch_bounds__(256, 2) void tree_leaves(const float* __restrict__ p,
                                                      const float* __restrict__ leaves,
                                                      float* __restrict__ out)
{
    __shared__ __align__(16) float pbuf[8][1024];   // p rows; reused as reduction buffer
    __shared__ __align__(16) float prob[8][1024];   // leaf probabilities

    const int tid = threadIdx.x;
    const int row_base = blockIdx.x * 8;

    // load 8 rows of p (8*1024 floats = 2048 float4, 8 per thread)
    {
        const float4* pg = reinterpret_cast<const float4*>(&p[(size_t)row_base * LDP]);
        float4* ps = reinterpret_cast<float4*>(&pbuf[0][0]);
        #pragma unroll
        for (int i = 0; i < 8; ++i)
            ps[tid + i * 256] = pg[tid + i * 256];
    }
    __syncthreads();

    // leaf probabilities: leaf l, level lvl: node=(2^lvl-1)+(l>>(10-lvl)),
    // bit=(l>>(9-lvl))&1; factor = bit? (1-p):p   (matches reference stacking order)
    for (int i = 0; i < 32; ++i) {
        const int r = i >> 2;
        const int l = ((i & 3) << 8) + tid;
        float pr = 1.0f;
        #pragma unroll
        for (int lvl = 0; lvl < 10; ++lvl) {
            const int node = (1 << lvl) - 1 + (l >> (10 - lvl));
            const float v = pbuf[r][node];
            const int bit = (l >> (9 - lvl)) & 1;
            pr *= bit ? (1.0f - v) : v;
        }
        prob[r][l] = pr;
    }
    __syncthreads();

    // out[r][d] = sum_l prob[r][l] * leaves[l][d]; thread owns (d, 256-leaf chunk)
    const int d = tid & 63;
    const int chunk = tid >> 6;
    float acc[8];
    #pragma unroll
    for (int r = 0; r < 8; ++r) acc[r] = 0.f;
    for (int i = 0; i < 256; ++i) {
        const int l = (chunk << 8) + i;
        const float lv = leaves[(size_t)l * 64 + d];   // coalesced 256B/wave
        #pragma unroll
        for (int r = 0; r < 8; ++r)
            acc[r] = fmaf(prob[r][l], lv, acc[r]);     // prob: LDS broadcast
    }

    // reduce 4 chunks via pbuf (free now), then write out
    float* red = &pbuf[0][0];
    #pragma unroll
    for (int r = 0; r < 8; ++r)
        red[(chunk * 8 + r) * 64 + d] = acc[r];
    __syncthreads();
    if (chunk == 0) {
        #pragma unroll
        for (int r = 0; r < 8; ++r) {
            const float s = red[(0 * 8 + r) * 64 + d] + red[(1 * 8 + r) * 64 + d]
                          + red[(2 * 8 + r) * 64 + d] + red[(3 * 8 + r) * 64 + d];
            out[(size_t)(row_base + r) * 64 + d] = s;
        }
    }
}

extern "C" void kernel_launch(void* const* d_in, const int* in_sizes, int n_in,
                              void* d_out, int out_size, void* d_ws, size_t ws_size,
                              hipStream_t stream) {
    const float* x      = (const float*)d_in[0];
    const float* W      = (const float*)d_in[1];
    const float* b      = (const float*)d_in[2];
    const float* leaves = (const float*)d_in[3];
    float* out = (float*)d_out;
    float* p   = (float*)d_ws;   // 8192*1024*4 = 33.55 MB

    dim3 gridA(16, 64);          // N-blocks x M-blocks
    gemm_sig<<<gridA, 256, 0, stream>>>(x, W, b, p);
    tree_leaves<<<1024, 256, 0, stream>>>(p, leaves, out);
}

// Round 2
// 135.210 us; speedup vs baseline: 1.8180x; 1.8180x over previous
//
#include <hip/hip_runtime.h>

// SoftTree on MI355X.
// Fast path: split-bf16 MFMA GEMM (xh@Wh + xh@Wl + xl@Wh) -> sigmoid -> p,
// then subtree-parallel tree expansion + dot with leaves.
// ws layout: p f32 [8192][1024] @0 (33.5MB), xh/xl bf16 [8192][512] @33.5/41.9MB,
//            wh/wl bf16 [1024][512] (W transposed, row n, col k) @50.3/51.4MB.
// NEED = 52,428,800 bytes; if ws smaller, fall back to fp32 VALU GEMM (round-1 code).

typedef short bf16x8 __attribute__((ext_vector_type(8)));
typedef float f32x4 __attribute__((ext_vector_type(4)));

#define GLOAD16(g, l) __builtin_amdgcn_global_load_lds( \
    (const __attribute__((address_space(1))) void*)(g), \
    (__attribute__((address_space(3))) void*)(l), 16, 0, 0)

__device__ __forceinline__ unsigned short f2bf(float f) {
    unsigned u = __float_as_uint(f);
    return (unsigned short)((u + 0x7FFFu + ((u >> 16) & 1u)) >> 16);
}

// ---------------- conversion: x -> xh+xl bf16; W -> Wt hi/lo bf16 (transposed, padded to 1024 rows)
__global__ __launch_bounds__(256) void convert_split(const float* __restrict__ x,
                                                     const float* __restrict__ W,
                                                     unsigned short* __restrict__ xh,
                                                     unsigned short* __restrict__ xl,
                                                     unsigned short* __restrict__ wh,
                                                     unsigned short* __restrict__ wl)
{
    __shared__ float tile[32][33];
    const int b = blockIdx.x;
    const int tid = threadIdx.x;
    if (b < 1024) {
        const float4* xs = reinterpret_cast<const float4*>(x);
        #pragma unroll
        for (int i = 0; i < 4; ++i) {
            const int idx = b * 1024 + i * 256 + tid;
            const float4 v = xs[idx];
            ushort4 h, l;
            h.x = f2bf(v.x); l.x = f2bf(v.x - __uint_as_float((unsigned)h.x << 16));
            h.y = f2bf(v.y); l.y = f2bf(v.y - __uint_as_float((unsigned)h.y << 16));
            h.z = f2bf(v.z); l.z = f2bf(v.z - __uint_as_float((unsigned)h.z << 16));
            h.w = f2bf(v.w); l.w = f2bf(v.w - __uint_as_float((unsigned)h.w << 16));
            reinterpret_cast<ushort4*>(xh)[idx] = h;
            reinterpret_cast<ushort4*>(xl)[idx] = l;
        }
    } else {
        // transpose W [512][1023] -> Wt [1024][512], zero-pad row 1023
        const int tb = b - 1024;             // 0..511
        const int k0 = (tb >> 5) * 32;       // 16 k-tiles
        const int n0 = (tb & 31) * 32;       // 32 n-tiles
        const int tk = tid >> 5, tn = tid & 31;
        #pragma unroll
        for (int j = 0; j < 4; ++j) {
            const int k = k0 + tk + j * 8;
            const int n = n0 + tn;
            tile[tk + j * 8][tn] = (n < 1023) ? W[(size_t)k * 1023 + n] : 0.f;
        }
        __syncthreads();
        const int wn = tid >> 5, wk = tid & 31;
        #pragma unroll
        for (int j = 0; j < 4; ++j) {
            const int n = n0 + wn + j * 8;
            const float v = tile[wk][wn + j * 8];
            const unsigned short h = f2bf(v);
            const unsigned short lo = f2bf(v - __uint_as_float((unsigned)h << 16));
            wh[(size_t)n * 512 + k0 + wk] = h;
            wl[(size_t)n * 512 + k0 + wk] = lo;
        }
    }
}

// ---------------- Kernel A (fast): p = sigmoid(x@W + b) via split-bf16 MFMA
// 128x128 tile, BK=32, 4 waves (2x2), 4x4 fragments of 16x16x32, 3 products.
__global__ __launch_bounds__(256, 2) void gemm_sig_mfma(
    const unsigned short* __restrict__ xh, const unsigned short* __restrict__ xl,
    const unsigned short* __restrict__ wh, const unsigned short* __restrict__ wl,
    const float* __restrict__ bias, float* __restrict__ p)
{
    __shared__ __align__(16) unsigned short Ah[128 * 32];
    __shared__ __align__(16) unsigned short Al[128 * 32];
    __shared__ __align__(16) unsigned short Bh[128 * 32];
    __shared__ __align__(16) unsigned short Bl[128 * 32];

    const int tid = threadIdx.x;
    const int lane = tid & 63;
    const int wv = tid >> 6;
    const int m_base = blockIdx.y * 128;
    const int n_base = blockIdx.x * 128;
    const int wr = wv >> 1, wc = wv & 1;

    f32x4 acc[4][4];
    #pragma unroll
    for (int i = 0; i < 4; ++i)
        #pragma unroll
        for (int j = 0; j < 4; ++j)
            acc[i][j] = (f32x4){0.f, 0.f, 0.f, 0.f};

    // staging: tile = 512 chunks of 16B (8 ushort); thread handles chunks tid, tid+256
    const int c0 = tid, c1 = tid + 256;
    const int lb0 = wv * 512;                 // LDS ushort offset, wave-uniform (i=0)
    const int lb1 = 2048 + wv * 512;          // i=1
    const int a0row = c0 >> 2, a0kc = (c0 & 3) * 8;
    const int a1row = c1 >> 2, a1kc = (c1 & 3) * 8;

    const int l15 = lane & 15, kg = lane >> 4;

    for (int k0 = 0; k0 < 512; k0 += 32) {
        GLOAD16(xh + (size_t)(m_base + a0row) * 512 + k0 + a0kc, Ah + lb0);
        GLOAD16(xh + (size_t)(m_base + a1row) * 512 + k0 + a1kc, Ah + lb1);
        GLOAD16(xl + (size_t)(m_base + a0row) * 512 + k0 + a0kc, Al + lb0);
        GLOAD16(xl + (size_t)(m_base + a1row) * 512 + k0 + a1kc, Al + lb1);
        GLOAD16(wh + (size_t)(n_base + a0row) * 512 + k0 + a0kc, Bh + lb0);
        GLOAD16(wh + (size_t)(n_base + a1row) * 512 + k0 + a1kc, Bh + lb1);
        GLOAD16(wl + (size_t)(n_base + a0row) * 512 + k0 + a0kc, Bl + lb0);
        GLOAD16(wl + (size_t)(n_base + a1row) * 512 + k0 + a1kc, Bl + lb1);
        __syncthreads();

        bf16x8 ah[4], al[4], bh[4], bl[4];
        #pragma unroll
        for (int mi = 0; mi < 4; ++mi) {
            const int off = (wr * 64 + mi * 16 + l15) * 32 + kg * 8;
            ah[mi] = *reinterpret_cast<const bf16x8*>(&Ah[off]);
            al[mi] = *reinterpret_cast<const bf16x8*>(&Al[off]);
        }
        #pragma unroll
        for (int ni = 0; ni < 4; ++ni) {
            const int off = (wc * 64 + ni * 16 + l15) * 32 + kg * 8;
            bh[ni] = *reinterpret_cast<const bf16x8*>(&Bh[off]);
            bl[ni] = *reinterpret_cast<const bf16x8*>(&Bl[off]);
        }
        #pragma unroll
        for (int mi = 0; mi < 4; ++mi)
            #pragma unroll
            for (int ni = 0; ni < 4; ++ni) {
                acc[mi][ni] = __builtin_amdgcn_mfma_f32_16x16x32_bf16(ah[mi], bh[ni], acc[mi][ni], 0, 0, 0);
                acc[mi][ni] = __builtin_amdgcn_mfma_f32_16x16x32_bf16(ah[mi], bl[ni], acc[mi][ni], 0, 0, 0);
                acc[mi][ni] = __builtin_amdgcn_mfma_f32_16x16x32_bf16(al[mi], bh[ni], acc[mi][ni], 0, 0, 0);
            }
        __syncthreads();
    }

    // epilogue: bias + sigmoid; C/D layout: col = lane&15, row = (lane>>4)*4 + r
    const int l4 = lane >> 4;
    #pragma unroll
    for (int ni = 0; ni < 4; ++ni) {
        const int n = n_base + wc * 64 + ni * 16 + l15;
        if (n < 1023) {
            const float bv = bias[n];
            #pragma unroll
            for (int mi = 0; mi < 4; ++mi) {
                #pragma unroll
                for (int r = 0; r < 4; ++r) {
                    const int m = m_base + wr * 64 + mi * 16 + l4 * 4 + r;
                    const float v = acc[mi][ni][r] + bv;
                    p[(size_t)m * 1024 + n] = 1.f / (1.f + __expf(-v));
                }
            }
        }
    }
}

// ---------------- Kernel A (fallback): round-1 fp32 VALU GEMM (known-good)
__global__ __launch_bounds__(256, 4) void gemm_sig_f32(const float* __restrict__ x,
                                                       const float* __restrict__ W,
                                                       const float* __restrict__ bias,
                                                       float* __restrict__ p)
{
    __shared__ __align__(16) float As[16][128 + 4];
    __shared__ __align__(16) float Bs[16][64 + 4];
    const int tid = threadIdx.x;
    const int m_base = blockIdx.y * 128;
    const int n_base = blockIdx.x * 64;
    const int m0 = (tid >> 4) * 8, n0 = (tid & 15) * 4;
    float acc[8][4];
    #pragma unroll
    for (int i = 0; i < 8; ++i)
        #pragma unroll
        for (int j = 0; j < 4; ++j) acc[i][j] = 0.f;
    const int arow = tid >> 2, acol = (tid & 3) * 4;
    const int bk = tid >> 4, bn = (tid & 15) * 4;
    for (int k0 = 0; k0 < 512; k0 += 16) {
        #pragma unroll
        for (int i = 0; i < 2; ++i) {
            const int row = arow + i * 64;
            const float4 a = *reinterpret_cast<const float4*>(&x[(size_t)(m_base + row) * 512 + k0 + acol]);
            As[0][(acol + 0) * 132 + row] = a.x;
            As[0][(acol + 1) * 132 + row] = a.y;
            As[0][(acol + 2) * 132 + row] = a.z;
            As[0][(acol + 3) * 132 + row] = a.w;
        }
        {
            const int gk = k0 + bk;
            #pragma unroll
            for (int j = 0; j < 4; ++j) {
                const int gn = n_base + bn + j;
                Bs[bk][bn + j] = (gn < 1023) ? W[(size_t)gk * 1023 + gn] : 0.f;
            }
        }
        __syncthreads();
        #pragma unroll
        for (int kk = 0; kk < 16; ++kk) {
            const float4 b4 = *reinterpret_cast<const float4*>(&Bs[kk][n0]);
            const float4 a0 = *reinterpret_cast<const float4*>(&As[kk][m0]);
            const float4 a1 = *reinterpret_cast<const float4*>(&As[kk][m0 + 4]);
            const float a[8] = {a0.x, a0.y, a0.z, a0.w, a1.x, a1.y, a1.z, a1.w};
            const float b[4] = {b4.x, b4.y, b4.z, b4.w};
            #pragma unroll
            for (int i = 0; i < 8; ++i)
                #pragma unroll
                for (int j = 0; j < 4; ++j)
                    acc[i][j] = fmaf(a[i], b[j], acc[i][j]);
        }
        __syncthreads();
    }
    #pragma unroll
    for (int i = 0; i < 8; ++i) {
        const int gm = m_base + m0 + i;
        #pragma unroll
        for (int j = 0; j < 4; ++j) {
            const int gn = n_base + n0 + j;
            if (gn < 1023) {
                float v = acc[i][j] + bias[gn];
                p[(size_t)gm * 1024 + gn] = 1.0f / (1.0f + __expf(-v));
            }
        }
    }
}

// ---------------- Kernel B: subtree tree-expansion + out = prob @ leaves
// 8 rows/block, 256 threads: thread (r = tid>>5, s = tid&31) expands subtree s
// of row r hierarchically (levels 5..9 in registers; prefix levels 0..4).
// LDS = 32KB (prob only) -> 5 blocks/CU.
__global__ __launch_bounds__(256, 4) void tree_leaves(const float* __restrict__ p,
                                                      const float* __restrict__ leaves,
                                                      float* __restrict__ out)
{
    __shared__ __align__(16) float prob[8][1024];   // 32 KB; reused for reduction

    const int tid = threadIdx.x;
    const int row_base = blockIdx.x * 8;
    const int r = tid >> 5, s = tid & 31;
    const float* pr = p + (size_t)(row_base + r) * 1024;

    // prefix: levels 0..4 along path to subtree s
    float prefix = 1.f;
    #pragma unroll
    for (int lvl = 0; lvl < 5; ++lvl) {
        const int node = (1 << lvl) - 1 + (s >> (5 - lvl));
        const float v = pr[node];
        prefix *= ((s >> (4 - lvl)) & 1) ? (1.f - v) : v;
    }

    // subtree levels 5..9 (fully static register expansion)
    float q1[2], q2[4], q3[8], q4[16], q5[32];
    {
        const float v = pr[31 + s];
        q1[0] = prefix * v; q1[1] = prefix * (1.f - v);
    }
    {
        const float va = pr[63 + 2 * s], vb = pr[64 + 2 * s];
        q2[0] = q1[0] * va; q2[1] = q1[0] * (1.f - va);
        q2[2] = q1[1] * vb; q2[3] = q1[1] * (1.f - vb);
    }
    #pragma unroll
    for (int j = 0; j < 4; ++j) {
        const float v = pr[127 + 4 * s + j];
        q3[2 * j] = q2[j] * v; q3[2 * j + 1] = q2[j] * (1.f - v);
    }
    #pragma unroll
    for (int j = 0; j < 8; ++j) {
        const float v = pr[255 + 8 * s + j];
        q4[2 * j] = q3[j] * v; q4[2 * j + 1] = q3[j] * (1.f - v);
    }
    #pragma unroll
    for (int j = 0; j < 16; ++j) {
        const float v = pr[511 + 16 * s + j];
        q5[2 * j] = q4[j] * v; q5[2 * j + 1] = q4[j] * (1.f - v);
    }

    // XOR-swizzled float4 LDS writes (avoid 32-way bank conflict; static reg indices)
    const int sw = (s & 7) << 2;
    #pragma unroll
    for (int u = 0; u < 32; u += 4) {
        float4 q; q.x = q5[u]; q.y = q5[u + 1]; q.z = q5[u + 2]; q.w = q5[u + 3];
        *reinterpret_cast<float4*>(&prob[r][s * 32 + (u ^ sw)]) = q;
    }
    __syncthreads();

    // dot: out[r][d] = sum_l prob[r][l] * leaves[l][d]
    const int d = tid & 63, chunk = tid >> 6;
    float acc2[8];
    #pragma unroll
    for (int i = 0; i < 8; ++i) acc2[i] = 0.f;
    const float* lvp = leaves + (size_t)(chunk << 8) * 64 + d;
    for (int i = 0; i < 256; i += 4) {
        const float l0 = lvp[(i + 0) * 64];
        const float l1 = lvp[(i + 1) * 64];
        const float l2 = lvp[(i + 2) * 64];
        const float l3 = lvp[(i + 3) * 64];
        const int base = (chunk << 8) + i;
        const int sblk = base >> 5;
        const int addr = (sblk << 5) + ((base & 31) ^ ((sblk & 7) << 2));  // un-swizzle
        #pragma unroll
        for (int r2 = 0; r2 < 8; ++r2) {
            const float4 pv = *reinterpret_cast<const float4*>(&prob[r2][addr]);
            acc2[r2] = fmaf(pv.x, l0, acc2[r2]);
            acc2[r2] = fmaf(pv.y, l1, acc2[r2]);
            acc2[r2] = fmaf(pv.z, l2, acc2[r2]);
            acc2[r2] = fmaf(pv.w, l3, acc2[r2]);
        }
    }

    // reduce 4 chunks (reuse prob LDS), write out
    __syncthreads();
    float* red = &prob[0][0];
    #pragma unroll
    for (int r2 = 0; r2 < 8; ++r2)
        red[(chunk * 8 + r2) * 64 + d] = acc2[r2];
    __syncthreads();
    if (chunk == 0) {
        #pragma unroll
        for (int r2 = 0; r2 < 8; ++r2) {
            const float sum = red[r2 * 64 + d] + red[(8 + r2) * 64 + d]
                            + red[(16 + r2) * 64 + d] + red[(24 + r2) * 64 + d];
            out[(size_t)(row_base + r2) * 64 + d] = sum;
        }
    }
}

extern "C" void kernel_launch(void* const* d_in, const int* in_sizes, int n_in,
                              void* d_out, int out_size, void* d_ws, size_t ws_size,
                              hipStream_t stream) {
    const float* x      = (const float*)d_in[0];
    const float* W      = (const float*)d_in[1];
    const float* b      = (const float*)d_in[2];
    const float* leaves = (const float*)d_in[3];
    float* out = (float*)d_out;

    float* p = (float*)d_ws;                                   // 33,554,432 B
    const size_t NEED = 52428800;

    if (ws_size >= NEED) {
        unsigned short* xh = (unsigned short*)((char*)d_ws + 33554432);
        unsigned short* xl = (unsigned short*)((char*)d_ws + 41943040);
        unsigned short* wh = (unsigned short*)((char*)d_ws + 50331648);
        unsigned short* wl = (unsigned short*)((char*)d_ws + 51380224);
        convert_split<<<1536, 256, 0, stream>>>(x, W, xh, xl, wh, wl);
        gemm_sig_mfma<<<dim3(8, 64), 256, 0, stream>>>(xh, xl, wh, wl, b, p);
    } else {
        gemm_sig_f32<<<dim3(16, 64), 256, 0, stream>>>(x, W, b, p);
    }
    tree_leaves<<<1024, 256, 0, stream>>>(p, leaves, out);
}

// Round 3
// 129.738 us; speedup vs baseline: 1.8947x; 1.0422x over previous
//
#include <hip/hip_runtime.h>

// SoftTree on MI355X — round 3.
// A: split-bf16 MFMA GEMM (xh@Wh + xh@Wl + xl@Wh), double-buffered LDS with
//    prefetch-before-compute (m97/T3-min schedule). Writes p SHIFTED +1 col:
//    p[m][1+node], so tree levels start 16B-aligned (level lvl at index 2^lvl).
// B: tree expansion reads p via aligned float4 (no LDS staging); prob in 32KB
//    swizzled LDS; dot with float4-of-d per thread (4x fewer LDS reads).
// ws: p f32 [8192][1024] @0, xh/xl bf16 [8192][512] @33.5/41.9MB,
//     wh/wl bf16 [1024][512] @50.3/51.4MB. NEED=52,428,800 B else fp32 fallback.

typedef short bf16x8 __attribute__((ext_vector_type(8)));
typedef float f32x4 __attribute__((ext_vector_type(4)));

#define GLOAD16(g, l) __builtin_amdgcn_global_load_lds( \
    (const __attribute__((address_space(1))) void*)(g), \
    (__attribute__((address_space(3))) void*)(l), 16, 0, 0)

__device__ __forceinline__ unsigned short f2bf(float f) {
    unsigned u = __float_as_uint(f);
    return (unsigned short)((u + 0x7FFFu + ((u >> 16) & 1u)) >> 16);
}

// ---------------- conversion: x -> xh+xl; W -> Wt hi/lo (transposed, padded)
__global__ __launch_bounds__(256) void convert_split(const float* __restrict__ x,
                                                     const float* __restrict__ W,
                                                     unsigned short* __restrict__ xh,
                                                     unsigned short* __restrict__ xl,
                                                     unsigned short* __restrict__ wh,
                                                     unsigned short* __restrict__ wl)
{
    __shared__ float tile[32][33];
    const int b = blockIdx.x;
    const int tid = threadIdx.x;
    if (b < 1024) {
        const float4* xs = reinterpret_cast<const float4*>(x);
        #pragma unroll
        for (int i = 0; i < 4; ++i) {
            const int idx = b * 1024 + i * 256 + tid;
            const float4 v = xs[idx];
            ushort4 h, l;
            h.x = f2bf(v.x); l.x = f2bf(v.x - __uint_as_float((unsigned)h.x << 16));
            h.y = f2bf(v.y); l.y = f2bf(v.y - __uint_as_float((unsigned)h.y << 16));
            h.z = f2bf(v.z); l.z = f2bf(v.z - __uint_as_float((unsigned)h.z << 16));
            h.w = f2bf(v.w); l.w = f2bf(v.w - __uint_as_float((unsigned)h.w << 16));
            reinterpret_cast<ushort4*>(xh)[idx] = h;
            reinterpret_cast<ushort4*>(xl)[idx] = l;
        }
    } else {
        const int tb = b - 1024;             // 0..511
        const int k0 = (tb >> 5) * 32;
        const int n0 = (tb & 31) * 32;
        const int tk = tid >> 5, tn = tid & 31;
        #pragma unroll
        for (int j = 0; j < 4; ++j) {
            const int k = k0 + tk + j * 8;
            const int n = n0 + tn;
            tile[tk + j * 8][tn] = (n < 1023) ? W[(size_t)k * 1023 + n] : 0.f;
        }
        __syncthreads();
        const int wn = tid >> 5, wk = tid & 31;
        #pragma unroll
        for (int j = 0; j < 4; ++j) {
            const int n = n0 + wn + j * 8;
            const float v = tile[wk][wn + j * 8];
            const unsigned short h = f2bf(v);
            const unsigned short lo = f2bf(v - __uint_as_float((unsigned)h << 16));
            wh[(size_t)n * 512 + k0 + wk] = h;
            wl[(size_t)n * 512 + k0 + wk] = lo;
        }
    }
}

// ---------------- Kernel A: p = sigmoid(x@W + b), split-bf16 MFMA, dbuf prefetch
__global__ __launch_bounds__(256, 2) void gemm_sig_mfma(
    const unsigned short* __restrict__ xh, const unsigned short* __restrict__ xl,
    const unsigned short* __restrict__ wh, const unsigned short* __restrict__ wl,
    const float* __restrict__ bias, float* __restrict__ p)
{
    __shared__ __align__(16) unsigned short Ah[2][128 * 32];
    __shared__ __align__(16) unsigned short Al[2][128 * 32];
    __shared__ __align__(16) unsigned short Bh[2][128 * 32];
    __shared__ __align__(16) unsigned short Bl[2][128 * 32];

    const int tid = threadIdx.x;
    const int lane = tid & 63;
    const int wv = tid >> 6;
    const int m_base = blockIdx.y * 128;
    const int n_base = blockIdx.x * 128;
    const int wr = wv >> 1, wc = wv & 1;

    f32x4 acc[4][4];
    #pragma unroll
    for (int i = 0; i < 4; ++i)
        #pragma unroll
        for (int j = 0; j < 4; ++j)
            acc[i][j] = (f32x4){0.f, 0.f, 0.f, 0.f};

    const int c0 = tid, c1 = tid + 256;
    const int lb0 = wv * 512;              // ushort offset within buffer (i=0)
    const int lb1 = 2048 + wv * 512;       // i=1
    const int a0row = c0 >> 2, a0kc = (c0 & 3) * 8;
    const int a1row = c1 >> 2, a1kc = (c1 & 3) * 8;
    const int l15 = lane & 15, kg = lane >> 4;

    const size_t ga0 = (size_t)(m_base + a0row) * 512 + a0kc;
    const size_t ga1 = (size_t)(m_base + a1row) * 512 + a1kc;
    const size_t gb0 = (size_t)(n_base + a0row) * 512 + a0kc;
    const size_t gb1 = (size_t)(n_base + a1row) * 512 + a1kc;

    #define STAGE(buf, k0) do { \
        GLOAD16(xh + ga0 + (k0), &Ah[buf][lb0]); \
        GLOAD16(xh + ga1 + (k0), &Ah[buf][lb1]); \
        GLOAD16(xl + ga0 + (k0), &Al[buf][lb0]); \
        GLOAD16(xl + ga1 + (k0), &Al[buf][lb1]); \
        GLOAD16(wh + gb0 + (k0), &Bh[buf][lb0]); \
        GLOAD16(wh + gb1 + (k0), &Bh[buf][lb1]); \
        GLOAD16(wl + gb0 + (k0), &Bl[buf][lb0]); \
        GLOAD16(wl + gb1 + (k0), &Bl[buf][lb1]); \
    } while (0)

    STAGE(0, 0);
    __syncthreads();

    #pragma unroll
    for (int t = 0; t < 16; ++t) {
        const int cur = t & 1;
        if (t < 15) STAGE(cur ^ 1, (t + 1) * 32);   // prefetch next tile

        bf16x8 ah[4], al[4], bh[4], bl[4];
        #pragma unroll
        for (int mi = 0; mi < 4; ++mi) {
            const int off = (wr * 64 + mi * 16 + l15) * 32 + kg * 8;
            ah[mi] = *reinterpret_cast<const bf16x8*>(&Ah[cur][off]);
            al[mi] = *reinterpret_cast<const bf16x8*>(&Al[cur][off]);
        }
        #pragma unroll
        for (int ni = 0; ni < 4; ++ni) {
            const int off = (wc * 64 + ni * 16 + l15) * 32 + kg * 8;
            bh[ni] = *reinterpret_cast<const bf16x8*>(&Bh[cur][off]);
            bl[ni] = *reinterpret_cast<const bf16x8*>(&Bl[cur][off]);
        }
        #pragma unroll
        for (int mi = 0; mi < 4; ++mi)
            #pragma unroll
            for (int ni = 0; ni < 4; ++ni) {
                acc[mi][ni] = __builtin_amdgcn_mfma_f32_16x16x32_bf16(ah[mi], bh[ni], acc[mi][ni], 0, 0, 0);
                acc[mi][ni] = __builtin_amdgcn_mfma_f32_16x16x32_bf16(ah[mi], bl[ni], acc[mi][ni], 0, 0, 0);
                acc[mi][ni] = __builtin_amdgcn_mfma_f32_16x16x32_bf16(al[mi], bh[ni], acc[mi][ni], 0, 0, 0);
            }
        __syncthreads();   // drains prefetch (vmcnt) + lds reads; next tile ready
    }
    #undef STAGE

    // epilogue: bias + sigmoid; store SHIFTED: p[m][1+n]
    const int l4 = lane >> 4;
    #pragma unroll
    for (int ni = 0; ni < 4; ++ni) {
        const int n = n_base + wc * 64 + ni * 16 + l15;
        if (n < 1023) {
            const float bv = bias[n];
            #pragma unroll
            for (int mi = 0; mi < 4; ++mi) {
                #pragma unroll
                for (int r = 0; r < 4; ++r) {
                    const int m = m_base + wr * 64 + mi * 16 + l4 * 4 + r;
                    const float v = acc[mi][ni][r] + bv;
                    p[(size_t)m * 1024 + 1 + n] = 1.f / (1.f + __expf(-v));
                }
            }
        }
    }
}

// ---------------- fallback fp32 GEMM (writes shifted p)
__global__ __launch_bounds__(256, 4) void gemm_sig_f32(const float* __restrict__ x,
                                                       const float* __restrict__ W,
                                                       const float* __restrict__ bias,
                                                       float* __restrict__ p)
{
    __shared__ __align__(16) float As[16][128 + 4];
    __shared__ __align__(16) float Bs[16][64 + 4];
    const int tid = threadIdx.x;
    const int m_base = blockIdx.y * 128;
    const int n_base = blockIdx.x * 64;
    const int m0 = (tid >> 4) * 8, n0 = (tid & 15) * 4;
    float acc[8][4];
    #pragma unroll
    for (int i = 0; i < 8; ++i)
        #pragma unroll
        for (int j = 0; j < 4; ++j) acc[i][j] = 0.f;
    const int arow = tid >> 2, acol = (tid & 3) * 4;
    const int bk = tid >> 4, bn = (tid & 15) * 4;
    for (int k0 = 0; k0 < 512; k0 += 16) {
        #pragma unroll
        for (int i = 0; i < 2; ++i) {
            const int row = arow + i * 64;
            const float4 a = *reinterpret_cast<const float4*>(&x[(size_t)(m_base + row) * 512 + k0 + acol]);
            As[0][(acol + 0) * 132 + row] = a.x;
            As[0][(acol + 1) * 132 + row] = a.y;
            As[0][(acol + 2) * 132 + row] = a.z;
            As[0][(acol + 3) * 132 + row] = a.w;
        }
        {
            const int gk = k0 + bk;
            #pragma unroll
            for (int j = 0; j < 4; ++j) {
                const int gn = n_base + bn + j;
                Bs[bk][bn + j] = (gn < 1023) ? W[(size_t)gk * 1023 + gn] : 0.f;
            }
        }
        __syncthreads();
        #pragma unroll
        for (int kk = 0; kk < 16; ++kk) {
            const float4 b4 = *reinterpret_cast<const float4*>(&Bs[kk][n0]);
            const float4 a0 = *reinterpret_cast<const float4*>(&As[kk][m0]);
            const float4 a1 = *reinterpret_cast<const float4*>(&As[kk][m0 + 4]);
            const float a[8] = {a0.x, a0.y, a0.z, a0.w, a1.x, a1.y, a1.z, a1.w};
            const float b[4] = {b4.x, b4.y, b4.z, b4.w};
            #pragma unroll
            for (int i = 0; i < 8; ++i)
                #pragma unroll
                for (int j = 0; j < 4; ++j)
                    acc[i][j] = fmaf(a[i], b[j], acc[i][j]);
        }
        __syncthreads();
    }
    #pragma unroll
    for (int i = 0; i < 8; ++i) {
        const int gm = m_base + m0 + i;
        #pragma unroll
        for (int j = 0; j < 4; ++j) {
            const int gn = n_base + n0 + j;
            if (gn < 1023) {
                float v = acc[i][j] + bias[gn];
                p[(size_t)gm * 1024 + 1 + gn] = 1.0f / (1.0f + __expf(-v));
            }
        }
    }
}

// ---------------- Kernel B: subtree expansion (aligned float4 reads) + dot
// 8 rows/block, 256 threads, LDS 32KB -> 4 blocks/CU.
// Expansion: thread (r=tid>>5, s=tid&31); p SHIFTED: level lvl starts at 2^lvl.
// Dot: thread (cg=tid>>4 owns 64 leaves, dg=tid&15 owns 4 d's), acc[8][4].
__global__ __launch_bounds__(256, 4) void tree_leaves(const float* __restrict__ p,
                                                      const float* __restrict__ leaves,
                                                      float* __restrict__ out)
{
    __shared__ __align__(16) float prob[8][1024];   // swizzled: col c at c^(((c>>5)&7)<<2)

    const int tid = threadIdx.x;
    const int row_base = blockIdx.x * 8;
    const int r = tid >> 5, s = tid & 31;
    const float* pr = p + (size_t)(row_base + r) * 1024;   // pr[1+node]

    // prefix levels 0..4
    float prefix = 1.f;
    #pragma unroll
    for (int lvl = 0; lvl < 5; ++lvl) {
        const float v = pr[(1 << lvl) + (s >> (5 - lvl))];
        prefix *= ((s >> (4 - lvl)) & 1) ? (1.f - v) : v;
    }

    // subtree levels 5..9, aligned vector loads
    float q1[2], q2[4], q3[8], q4[16], q5[32];
    {
        const float v = pr[32 + s];
        q1[0] = prefix * v; q1[1] = prefix * (1.f - v);
    }
    {
        const float2 v2 = *reinterpret_cast<const float2*>(&pr[64 + 2 * s]);
        q2[0] = q1[0] * v2.x; q2[1] = q1[0] * (1.f - v2.x);
        q2[2] = q1[1] * v2.y; q2[3] = q1[1] * (1.f - v2.y);
    }
    {
        const float4 v4 = *reinterpret_cast<const float4*>(&pr[128 + 4 * s]);
        const float v[4] = {v4.x, v4.y, v4.z, v4.w};
        #pragma unroll
        for (int j = 0; j < 4; ++j) {
            q3[2 * j] = q2[j] * v[j]; q3[2 * j + 1] = q2[j] * (1.f - v[j]);
        }
    }
    {
        const float4 va = *reinterpret_cast<const float4*>(&pr[256 + 8 * s]);
        const float4 vb = *reinterpret_cast<const float4*>(&pr[260 + 8 * s]);
        const float v[8] = {va.x, va.y, va.z, va.w, vb.x, vb.y, vb.z, vb.w};
        #pragma unroll
        for (int j = 0; j < 8; ++j) {
            q4[2 * j] = q3[j] * v[j]; q4[2 * j + 1] = q3[j] * (1.f - v[j]);
        }
    }
    {
        float v[16];
        #pragma unroll
        for (int u = 0; u < 4; ++u) {
            const float4 vv = *reinterpret_cast<const float4*>(&pr[512 + 16 * s + 4 * u]);
            v[4 * u] = vv.x; v[4 * u + 1] = vv.y; v[4 * u + 2] = vv.z; v[4 * u + 3] = vv.w;
        }
        #pragma unroll
        for (int j = 0; j < 16; ++j) {
            q5[2 * j] = q4[j] * v[j]; q5[2 * j + 1] = q4[j] * (1.f - v[j]);
        }
    }

    // swizzled float4 LDS writes
    const int sw = (s & 7) << 2;
    #pragma unroll
    for (int u = 0; u < 32; u += 4) {
        float4 q; q.x = q5[u]; q.y = q5[u + 1]; q.z = q5[u + 2]; q.w = q5[u + 3];
        *reinterpret_cast<float4*>(&prob[r][s * 32 + (u ^ sw)]) = q;
    }
    __syncthreads();

    // dot: out[r][dg*4..+3] partial over leaves [cg*64, cg*64+64)
    const int cg = tid >> 4, dg = tid & 15;
    float acc[8][4];
    #pragma unroll
    for (int i = 0; i < 8; ++i)
        #pragma unroll
        for (int j = 0; j < 4; ++j) acc[i][j] = 0.f;

    const float* lv_base = leaves + (size_t)(cg * 64) * 64 + dg * 4;
    #pragma unroll 4
    for (int i4 = 0; i4 < 16; ++i4) {
        const int l0 = cg * 64 + i4 * 4;
        const int m_ = (cg * 2 + (i4 >> 3)) & 7;
        const int col = (cg * 64 + ((i4 * 4) ^ (m_ << 2)));
        float4 lv[4];
        #pragma unroll
        for (int j = 0; j < 4; ++j)
            lv[j] = *reinterpret_cast<const float4*>(&leaves[(size_t)(l0 + j) * 64 + dg * 4]);
        #pragma unroll
        for (int rr = 0; rr < 8; ++rr) {
            const float4 pv = *reinterpret_cast<const float4*>(&prob[rr][col]);
            const float pvv[4] = {pv.x, pv.y, pv.z, pv.w};
            #pragma unroll
            for (int j = 0; j < 4; ++j) {
                acc[rr][0] = fmaf(pvv[j], lv[j].x, acc[rr][0]);
                acc[rr][1] = fmaf(pvv[j], lv[j].y, acc[rr][1]);
                acc[rr][2] = fmaf(pvv[j], lv[j].z, acc[rr][2]);
                acc[rr][3] = fmaf(pvv[j], lv[j].w, acc[rr][3]);
            }
        }
    }
    (void)lv_base;

    // 16-way chunk reduction via LDS (overlay prob), then write out
    __syncthreads();
    float* red = &prob[0][0];                      // [cg*8+r][64]
    #pragma unroll
    for (int rr = 0; rr < 8; ++rr) {
        float4 q; q.x = acc[rr][0]; q.y = acc[rr][1]; q.z = acc[rr][2]; q.w = acc[rr][3];
        *reinterpret_cast<float4*>(&red[(size_t)(cg * 8 + rr) * 64 + dg * 4]) = q;
    }
    __syncthreads();
    #pragma unroll
    for (int o = tid; o < 512; o += 256) {
        const int rr = o >> 6, d = o & 63;
        float sum = 0.f;
        #pragma unroll
        for (int c = 0; c < 16; ++c)
            sum += red[(size_t)(c * 8 + rr) * 64 + d];
        out[(size_t)(row_base + rr) * 64 + d] = sum;
    }
}

extern "C" void kernel_launch(void* const* d_in, const int* in_sizes, int n_in,
                              void* d_out, int out_size, void* d_ws, size_t ws_size,
                              hipStream_t stream) {
    const float* x      = (const float*)d_in[0];
    const float* W      = (const float*)d_in[1];
    const float* b      = (const float*)d_in[2];
    const float* leaves = (const float*)d_in[3];
    float* out = (float*)d_out;

    float* p = (float*)d_ws;
    const size_t NEED = 52428800;

    if (ws_size >= NEED) {
        unsigned short* xh = (unsigned short*)((char*)d_ws + 33554432);
        unsigned short* xl = (unsigned short*)((char*)d_ws + 41943040);
        unsigned short* wh = (unsigned short*)((char*)d_ws + 50331648);
        unsigned short* wl = (unsigned short*)((char*)d_ws + 51380224);
        convert_split<<<1536, 256, 0, stream>>>(x, W, xh, xl, wh, wl);
        gemm_sig_mfma<<<dim3(8, 64), 256, 0, stream>>>(xh, xl, wh, wl, b, p);
    } else {
        gemm_sig_f32<<<dim3(16, 64), 256, 0, stream>>>(x, W, b, p);
    }
    tree_leaves<<<1024, 256, 0, stream>>>(p, leaves, out);
}

// Round 5
// 118.942 us; speedup vs baseline: 2.0667x; 1.0908x over previous
//
#include <hip/hip_runtime.h>

// SoftTree on MI355X — round 4 resubmit (R4 bench never acquired a GPU).
// A: fp16 2-product MFMA GEMM: p = sigmoid(xh@(Wh+Wl) + b), xh=fp16(x),
//    Wh/Wl = fp16 hi/lo split of W. 128x128 tile, BK=32, 512 threads (8 waves,
//    4x2), dbuf LDS 48KB, 2 blocks/CU -> 4 waves/SIMD. p written SHIFTED +1 col.
// B: tree expansion + dot (unchanged from round 3).
// ws: p f32 [8192][1024] @0, xh fp16 [8192][512] @33.5MB, wh/wl fp16 [1024][512]
//     @41.94/42.99MB. NEED=44,040,192 B else fp32 fallback.

typedef _Float16 f16x8 __attribute__((ext_vector_type(8)));
typedef float f32x4 __attribute__((ext_vector_type(4)));

#define GLOAD16(g, l) __builtin_amdgcn_global_load_lds( \
    (const __attribute__((address_space(1))) void*)(g), \
    (__attribute__((address_space(3))) void*)(l), 16, 0, 0)

// ---------------- conversion: x -> xh fp16; W -> Wt hi/lo fp16 (transposed, padded)
__global__ __launch_bounds__(256) void convert_split(const float* __restrict__ x,
                                                     const float* __restrict__ W,
                                                     _Float16* __restrict__ xh,
                                                     _Float16* __restrict__ wh,
                                                     _Float16* __restrict__ wl)
{
    __shared__ float tile[32][33];
    const int b = blockIdx.x;
    const int tid = threadIdx.x;
    if (b < 1024) {
        // 16 floats per thread -> 16 halves (two 16B stores)
        const int t = b * 256 + tid;
        const float4* xs = reinterpret_cast<const float4*>(x) + (size_t)t * 4;
        f16x8 o0, o1;
        #pragma unroll
        for (int i = 0; i < 2; ++i) {
            const float4 v0 = xs[i * 2 + 0];
            const float4 v1 = xs[i * 2 + 1];
            f16x8 o;
            o[0] = (_Float16)v0.x; o[1] = (_Float16)v0.y;
            o[2] = (_Float16)v0.z; o[3] = (_Float16)v0.w;
            o[4] = (_Float16)v1.x; o[5] = (_Float16)v1.y;
            o[6] = (_Float16)v1.z; o[7] = (_Float16)v1.w;
            if (i == 0) o0 = o; else o1 = o;
        }
        reinterpret_cast<f16x8*>(xh)[(size_t)t * 2 + 0] = o0;
        reinterpret_cast<f16x8*>(xh)[(size_t)t * 2 + 1] = o1;
    } else {
        // transpose W [512][1023] -> Wt [1024][512] fp16 hi/lo, zero-pad row 1023
        const int tb = b - 1024;             // 0..511
        const int k0 = (tb >> 5) * 32;
        const int n0 = (tb & 31) * 32;
        const int tk = tid >> 5, tn = tid & 31;
        #pragma unroll
        for (int j = 0; j < 4; ++j) {
            const int k = k0 + tk + j * 8;
            const int n = n0 + tn;
            tile[tk + j * 8][tn] = (n < 1023) ? W[(size_t)k * 1023 + n] : 0.f;
        }
        __syncthreads();
        const int wn = tid >> 5, wk = tid & 31;
        #pragma unroll
        for (int j = 0; j < 4; ++j) {
            const int n = n0 + wn + j * 8;
            const float v = tile[wk][wn + j * 8];
            const _Float16 h = (_Float16)v;
            const _Float16 lo = (_Float16)(v - (float)h);
            wh[(size_t)n * 512 + k0 + wk] = h;
            wl[(size_t)n * 512 + k0 + wk] = lo;
        }
    }
}

// ---------------- Kernel A: p = sigmoid(x@W + b), fp16 2-product MFMA
__global__ __launch_bounds__(512, 4) void gemm_sig_mfma(
    const _Float16* __restrict__ xh,
    const _Float16* __restrict__ wh, const _Float16* __restrict__ wl,
    const float* __restrict__ bias, float* __restrict__ p)
{
    __shared__ __align__(16) _Float16 A_[2][128 * 32];   // 16 KB
    __shared__ __align__(16) _Float16 Bh_[2][128 * 32];  // 16 KB
    __shared__ __align__(16) _Float16 Bl_[2][128 * 32];  // 16 KB

    const int tid = threadIdx.x;
    const int lane = tid & 63;
    const int wv = tid >> 6;            // 0..7
    const int m_base = blockIdx.y * 128;
    const int n_base = blockIdx.x * 128;
    const int wr = wv >> 1, wc = wv & 1; // 4x2 wave grid; wave tile 32x64

    f32x4 acc[2][4];
    #pragma unroll
    for (int i = 0; i < 2; ++i)
        #pragma unroll
        for (int j = 0; j < 4; ++j)
            acc[i][j] = (f32x4){0.f, 0.f, 0.f, 0.f};

    // staging: tile = 512 chunks of 16B (8 halves); one chunk per thread
    const int row = tid >> 2;
    const int oct = (tid & 3) * 8;
    const int lb = wv * 512;            // half-units; HW adds lane*16B
    const size_t ga = (size_t)(m_base + row) * 512 + oct;
    const size_t gb = (size_t)(n_base + row) * 512 + oct;

    const int l15 = lane & 15, kg = lane >> 4;

    #define STAGE(buf, k0) do { \
        GLOAD16(xh + ga + (k0), &A_[buf][lb]);  \
        GLOAD16(wh + gb + (k0), &Bh_[buf][lb]); \
        GLOAD16(wl + gb + (k0), &Bl_[buf][lb]); \
    } while (0)

    STAGE(0, 0);
    __syncthreads();

    #pragma unroll
    for (int t = 0; t < 16; ++t) {
        const int cur = t & 1;
        if (t < 15) STAGE(cur ^ 1, (t + 1) * 32);   // prefetch next tile

        f16x8 a_[2], bh_[4], bl_[4];
        #pragma unroll
        for (int mi = 0; mi < 2; ++mi) {
            const int off = (wr * 32 + mi * 16 + l15) * 32 + kg * 8;
            a_[mi] = *reinterpret_cast<const f16x8*>(&A_[cur][off]);
        }
        #pragma unroll
        for (int ni = 0; ni < 4; ++ni) {
            const int off = (wc * 64 + ni * 16 + l15) * 32 + kg * 8;
            bh_[ni] = *reinterpret_cast<const f16x8*>(&Bh_[cur][off]);
            bl_[ni] = *reinterpret_cast<const f16x8*>(&Bl_[cur][off]);
        }
        #pragma unroll
        for (int mi = 0; mi < 2; ++mi)
            #pragma unroll
            for (int ni = 0; ni < 4; ++ni) {
                acc[mi][ni] = __builtin_amdgcn_mfma_f32_16x16x32_f16(a_[mi], bh_[ni], acc[mi][ni], 0, 0, 0);
                acc[mi][ni] = __builtin_amdgcn_mfma_f32_16x16x32_f16(a_[mi], bl_[ni], acc[mi][ni], 0, 0, 0);
            }
        __syncthreads();   // drains prefetch vmcnt + lds reads
    }
    #undef STAGE

    // epilogue: bias + sigmoid; store SHIFTED: p[m][1+n]
    const int l4 = lane >> 4;
    #pragma unroll
    for (int ni = 0; ni < 4; ++ni) {
        const int n = n_base + wc * 64 + ni * 16 + l15;
        if (n < 1023) {
            const float bv = bias[n];
            #pragma unroll
            for (int mi = 0; mi < 2; ++mi) {
                #pragma unroll
                for (int r = 0; r < 4; ++r) {
                    const int m = m_base + wr * 32 + mi * 16 + l4 * 4 + r;
                    const float v = acc[mi][ni][r] + bv;
                    p[(size_t)m * 1024 + 1 + n] = 1.f / (1.f + __expf(-v));
                }
            }
        }
    }
}

// ---------------- fallback fp32 GEMM (writes shifted p)
__global__ __launch_bounds__(256, 4) void gemm_sig_f32(const float* __restrict__ x,
                                                       const float* __restrict__ W,
                                                       const float* __restrict__ bias,
                                                       float* __restrict__ p)
{
    __shared__ __align__(16) float As[16][128 + 4];
    __shared__ __align__(16) float Bs[16][64 + 4];
    const int tid = threadIdx.x;
    const int m_base = blockIdx.y * 128;
    const int n_base = blockIdx.x * 64;
    const int m0 = (tid >> 4) * 8, n0 = (tid & 15) * 4;
    float acc[8][4];
    #pragma unroll
    for (int i = 0; i < 8; ++i)
        #pragma unroll
        for (int j = 0; j < 4; ++j) acc[i][j] = 0.f;
    const int arow = tid >> 2, acol = (tid & 3) * 4;
    const int bk = tid >> 4, bn = (tid & 15) * 4;
    for (int k0 = 0; k0 < 512; k0 += 16) {
        #pragma unroll
        for (int i = 0; i < 2; ++i) {
            const int row = arow + i * 64;
            const float4 a = *reinterpret_cast<const float4*>(&x[(size_t)(m_base + row) * 512 + k0 + acol]);
            As[0][(acol + 0) * 132 + row] = a.x;
            As[0][(acol + 1) * 132 + row] = a.y;
            As[0][(acol + 2) * 132 + row] = a.z;
            As[0][(acol + 3) * 132 + row] = a.w;
        }
        {
            const int gk = k0 + bk;
            #pragma unroll
            for (int j = 0; j < 4; ++j) {
                const int gn = n_base + bn + j;
                Bs[bk][bn + j] = (gn < 1023) ? W[(size_t)gk * 1023 + gn] : 0.f;
            }
        }
        __syncthreads();
        #pragma unroll
        for (int kk = 0; kk < 16; ++kk) {
            const float4 b4 = *reinterpret_cast<const float4*>(&Bs[kk][n0]);
            const float4 a0 = *reinterpret_cast<const float4*>(&As[kk][m0]);
            const float4 a1 = *reinterpret_cast<const float4*>(&As[kk][m0 + 4]);
            const float a[8] = {a0.x, a0.y, a0.z, a0.w, a1.x, a1.y, a1.z, a1.w};
            const float b[4] = {b4.x, b4.y, b4.z, b4.w};
            #pragma unroll
            for (int i = 0; i < 8; ++i)
                #pragma unroll
                for (int j = 0; j < 4; ++j)
                    acc[i][j] = fmaf(a[i], b[j], acc[i][j]);
        }
        __syncthreads();
    }
    #pragma unroll
    for (int i = 0; i < 8; ++i) {
        const int gm = m_base + m0 + i;
        #pragma unroll
        for (int j = 0; j < 4; ++j) {
            const int gn = n_base + n0 + j;
            if (gn < 1023) {
                float v = acc[i][j] + bias[gn];
                p[(size_t)gm * 1024 + 1 + gn] = 1.0f / (1.0f + __expf(-v));
            }
        }
    }
}

// ---------------- Kernel B: subtree expansion + dot (UNCHANGED from round 3)
__global__ __launch_bounds__(256, 4) void tree_leaves(const float* __restrict__ p,
                                                      const float* __restrict__ leaves,
                                                      float* __restrict__ out)
{
    __shared__ __align__(16) float prob[8][1024];

    const int tid = threadIdx.x;
    const int row_base = blockIdx.x * 8;
    const int r = tid >> 5, s = tid & 31;
    const float* pr = p + (size_t)(row_base + r) * 1024;   // pr[1+node]

    float prefix = 1.f;
    #pragma unroll
    for (int lvl = 0; lvl < 5; ++lvl) {
        const float v = pr[(1 << lvl) + (s >> (5 - lvl))];
        prefix *= ((s >> (4 - lvl)) & 1) ? (1.f - v) : v;
    }

    float q1[2], q2[4], q3[8], q4[16], q5[32];
    {
        const float v = pr[32 + s];
        q1[0] = prefix * v; q1[1] = prefix * (1.f - v);
    }
    {
        const float2 v2 = *reinterpret_cast<const float2*>(&pr[64 + 2 * s]);
        q2[0] = q1[0] * v2.x; q2[1] = q1[0] * (1.f - v2.x);
        q2[2] = q1[1] * v2.y; q2[3] = q1[1] * (1.f - v2.y);
    }
    {
        const float4 v4 = *reinterpret_cast<const float4*>(&pr[128 + 4 * s]);
        const float v[4] = {v4.x, v4.y, v4.z, v4.w};
        #pragma unroll
        for (int j = 0; j < 4; ++j) {
            q3[2 * j] = q2[j] * v[j]; q3[2 * j + 1] = q2[j] * (1.f - v[j]);
        }
    }
    {
        const float4 va = *reinterpret_cast<const float4*>(&pr[256 + 8 * s]);
        const float4 vb = *reinterpret_cast<const float4*>(&pr[260 + 8 * s]);
        const float v[8] = {va.x, va.y, va.z, va.w, vb.x, vb.y, vb.z, vb.w};
        #pragma unroll
        for (int j = 0; j < 8; ++j) {
            q4[2 * j] = q3[j] * v[j]; q4[2 * j + 1] = q3[j] * (1.f - v[j]);
        }
    }
    {
        float v[16];
        #pragma unroll
        for (int u = 0; u < 4; ++u) {
            const float4 vv = *reinterpret_cast<const float4*>(&pr[512 + 16 * s + 4 * u]);
            v[4 * u] = vv.x; v[4 * u + 1] = vv.y; v[4 * u + 2] = vv.z; v[4 * u + 3] = vv.w;
        }
        #pragma unroll
        for (int j = 0; j < 16; ++j) {
            q5[2 * j] = q4[j] * v[j]; q5[2 * j + 1] = q4[j] * (1.f - v[j]);
        }
    }

    const int sw = (s & 7) << 2;
    #pragma unroll
    for (int u = 0; u < 32; u += 4) {
        float4 q; q.x = q5[u]; q.y = q5[u + 1]; q.z = q5[u + 2]; q.w = q5[u + 3];
        *reinterpret_cast<float4*>(&prob[r][s * 32 + (u ^ sw)]) = q;
    }
    __syncthreads();

    const int cg = tid >> 4, dg = tid & 15;
    float acc[8][4];
    #pragma unroll
    for (int i = 0; i < 8; ++i)
        #pragma unroll
        for (int j = 0; j < 4; ++j) acc[i][j] = 0.f;

    #pragma unroll 4
    for (int i4 = 0; i4 < 16; ++i4) {
        const int l0 = cg * 64 + i4 * 4;
        const int m_ = (cg * 2 + (i4 >> 3)) & 7;
        const int col = (cg * 64 + ((i4 * 4) ^ (m_ << 2)));
        float4 lv[4];
        #pragma unroll
        for (int j = 0; j < 4; ++j)
            lv[j] = *reinterpret_cast<const float4*>(&leaves[(size_t)(l0 + j) * 64 + dg * 4]);
        #pragma unroll
        for (int rr = 0; rr < 8; ++rr) {
            const float4 pv = *reinterpret_cast<const float4*>(&prob[rr][col]);
            const float pvv[4] = {pv.x, pv.y, pv.z, pv.w};
            #pragma unroll
            for (int j = 0; j < 4; ++j) {
                acc[rr][0] = fmaf(pvv[j], lv[j].x, acc[rr][0]);
                acc[rr][1] = fmaf(pvv[j], lv[j].y, acc[rr][1]);
                acc[rr][2] = fmaf(pvv[j], lv[j].z, acc[rr][2]);
                acc[rr][3] = fmaf(pvv[j], lv[j].w, acc[rr][3]);
            }
        }
    }

    __syncthreads();
    float* red = &prob[0][0];
    #pragma unroll
    for (int rr = 0; rr < 8; ++rr) {
        float4 q; q.x = acc[rr][0]; q.y = acc[rr][1]; q.z = acc[rr][2]; q.w = acc[rr][3];
        *reinterpret_cast<float4*>(&red[(size_t)(cg * 8 + rr) * 64 + dg * 4]) = q;
    }
    __syncthreads();
    #pragma unroll
    for (int o = tid; o < 512; o += 256) {
        const int rr = o >> 6, d = o & 63;
        float sum = 0.f;
        #pragma unroll
        for (int c = 0; c < 16; ++c)
            sum += red[(size_t)(c * 8 + rr) * 64 + d];
        out[(size_t)(row_base + rr) * 64 + d] = sum;
    }
}

extern "C" void kernel_launch(void* const* d_in, const int* in_sizes, int n_in,
                              void* d_out, int out_size, void* d_ws, size_t ws_size,
                              hipStream_t stream) {
    const float* x      = (const float*)d_in[0];
    const float* W      = (const float*)d_in[1];
    const float* b      = (const float*)d_in[2];
    const float* leaves = (const float*)d_in[3];
    float* out = (float*)d_out;

    float* p = (float*)d_ws;
    const size_t NEED = 44040192;

    if (ws_size >= NEED) {
        _Float16* xh = (_Float16*)((char*)d_ws + 33554432);
        _Float16* wh = (_Float16*)((char*)d_ws + 41943040);
        _Float16* wl = (_Float16*)((char*)d_ws + 42991616);
        convert_split<<<1536, 256, 0, stream>>>(x, W, xh, wh, wl);
        gemm_sig_mfma<<<dim3(8, 64), 512, 0, stream>>>(xh, wh, wl, b, p);
    } else {
        gemm_sig_f32<<<dim3(16, 64), 256, 0, stream>>>(x, W, b, p);
    }
    tree_leaves<<<1024, 256, 0, stream>>>(p, leaves, out);
}